// Round 4
// baseline (196.674 us; speedup 1.0000x reference)
//
#include <hip/hip_runtime.h>
#include <math.h>

#define CI   256
#define CO   256
#define HW   56
#define LQ   7
#define BETA 10.0f

typedef __attribute__((ext_vector_type(8)))  short short8;
typedef __attribute__((ext_vector_type(16))) float f32x16;
typedef __attribute__((ext_vector_type(4)))  float f32x4;

__device__ __forceinline__ ushort f2bf(float f) {
    uint u = __float_as_uint(f);
    u += 0x7FFF + ((u >> 16) & 1);
    return (ushort)(u >> 16);
}

// ---------------- Kernel 1: soft-quantize weights -> packed bf16 ----------------
// W2 layout: [chunk 8][tap 9][kb 4][co 256][e 8] bf16  (k = chunk*32 + kb*8 + e)
// one thread per (co, ci, tap): contiguous 28B reads, 7 expf each
__global__ __launch_bounds__(256) void quant_weights(const float* __restrict__ p_c,
                                                     const float* __restrict__ q_level,
                                                     short* __restrict__ W2) {
    int idx = blockIdx.x * 256 + threadIdx.x;  // (co*256+ci)*9 + t
    if (idx >= CO * CI * 9) return;
    int coci = idx / 9;
    int t = idx - coci * 9;
    int co = coci >> 8, ci = coci & 255;
    const float* p = p_c + (size_t)idx * LQ;
    float pv[LQ];
    float ss = 0.f;
#pragma unroll
    for (int l = 0; l < LQ; ++l) { pv[l] = p[l]; ss += pv[l] * pv[l]; }
    float inv = rsqrtf(ss) * BETA;
    float m = -1e30f;
#pragma unroll
    for (int l = 0; l < LQ; ++l) { pv[l] *= inv; m = fmaxf(m, pv[l]); }
    float den = 0.f, num = 0.f;
#pragma unroll
    for (int l = 0; l < LQ; ++l) {
        float e = expf(pv[l] - m);
        den += e;
        num += e * q_level[l];
    }
    int widx = ((((ci >> 5) * 9 + t) * 4 + ((ci >> 3) & 3)) * 2048) + co * 8 + (ci & 7);
    W2[widx] = (short)f2bf(num / den);
}

// ---------------- Pre-pass: NCHW f32 -> padded NHWC bf16, border fused ----------------
// x_t: [32][58][58][256] bf16, x_t[b][h+1][w+1][ci] = bf16(x[b][ci][h][w]), borders 0
__global__ __launch_bounds__(256) void prep_main(const float* __restrict__ x,
                                                 ushort* __restrict__ xt) {
    __shared__ ushort ld[256 * 60];
    const int tid = threadIdx.x;
    const int h = blockIdx.x;   // 0..55
    const int b = blockIdx.y;

    // fused border zeroing: full rows 0/57 (by edge blocks), cols 0/57 of row h+1
    if (h == 0 || h == 55) {
        int rr = (h == 0) ? 0 : 57;
        size_t base = ((size_t)b * 58 + rr) * 58 * 256;
        uint4 z = {0, 0, 0, 0};
        for (int i = tid; i < 58 * 256 / 8; i += 256)
            *(uint4*)&xt[base + (size_t)i * 8] = z;
    }
    if (tid < 64) {
        int col = (tid >> 5) * 57;
        int chk = tid & 31;
        size_t o = (((size_t)b * 58 + h + 1) * 58 + col) * 256 + chk * 8;
        uint4 z = {0, 0, 0, 0};
        *(uint4*)&xt[o] = z;
    }

    const float* xp = x + ((size_t)b * CI) * 3136 + h * HW;
#pragma unroll
    for (int s = 0; s < 14; ++s) {
        int flat = s * 1024 + tid * 4;  // 256*56 elems, 14 steps exact
        int ci = flat / 56;
        int w  = flat - ci * 56;
        const float4 v = *(const float4*)(xp + (size_t)ci * 3136 + w);
        ushort4 o;
        o.x = f2bf(v.x); o.y = f2bf(v.y); o.z = f2bf(v.z); o.w = f2bf(v.w);
        *(ushort4*)&ld[ci * 60 + w] = o;
    }
    __syncthreads();
    const int w = tid & 63;
    const int wq = tid >> 6;
    if (w < 56) {
        size_t obase = (((size_t)b * 58 + h + 1) * 58 + (w + 1)) * 256;
#pragma unroll
        for (int s = 0; s < 8; ++s) {
            int cig = s * 4 + wq;
            int base = (cig * 8) * 60 + w;
            uint u0 = (uint)ld[base]       | ((uint)ld[base + 60]  << 16);
            uint u1 = (uint)ld[base + 120] | ((uint)ld[base + 180] << 16);
            uint u2 = (uint)ld[base + 240] | ((uint)ld[base + 300] << 16);
            uint u3 = (uint)ld[base + 360] | ((uint)ld[base + 420] << 16);
            uint4 o = {u0, u1, u2, u3};
            *(uint4*)&xt[obase + cig * 8] = o;
        }
    }
}

// ---------------- Kernel 2 (fast): implicit-GEMM conv, 32x32x16 MFMA ----------------
// block: 256 thr = 4 waves (2 co-halves x 2 rows); tile 128co x (2 rows x 64 w)
// wave tile: 64co x 64n via 2x2 frags of 32x32, acc = 64 VGPR -> 3 waves/SIMD
// LDS/buffer: 1056 groups of 16B: gg=(r*66+c)*4+kbq holds
//   x_t[b][h0+r][min(c,57)][ci0 + (kbq ^ ((c>>1)&3))*8 ..+8]
__global__ __launch_bounds__(256, 3) void conv_mfma3(const ushort* __restrict__ xt_g,
                                                     const short* __restrict__ W2,
                                                     float* __restrict__ out) {
    __shared__ __align__(16) ushort xt[2][8448];  // 2 x 16896 B

    const int tid  = threadIdx.x;
    const int lane = tid & 63;
    const int wv   = tid >> 6;
    const int l31  = lane & 31;
    const int hi   = lane >> 5;       // k-subgroup within K-half
    const int wm   = (wv >> 1) * 64;  // wave co offset
    const int wn   = wv & 1;          // wave output row

    const int h0  = blockIdx.x * 2;
    const int co0 = blockIdx.y * 128;
    const int b   = blockIdx.z;

    // per-thread staging source offsets (5 steps; step 4 has 8 active lanes)
    int src_off[5];
#pragma unroll
    for (int s = 0; s < 5; ++s) {
        int gl = s * 64 + lane;
        int g  = wv * 264 + (gl < 264 ? gl : 0);
        int kbq = g & 3, pos = g >> 2;
        int r = pos / 66, c = pos - r * 66;
        int cc = c < 58 ? c : 57;          // c>=58 only feeds discarded w>=56
        int cig = kbq ^ ((c >> 1) & 3);    // swizzle on global source (m173)
        src_off[s] = ((b * 58 + h0 + r) * 58 + cc) * 256 + cig * 8;
    }

    f32x16 acc[2][2];
#pragma unroll
    for (int a = 0; a < 2; ++a)
#pragma unroll
        for (int f = 0; f < 2; ++f)
#pragma unroll
            for (int j = 0; j < 16; ++j) acc[a][f][j] = 0.f;

    // prologue: stage chunk 0 into buf 0
#pragma unroll
    for (int s = 0; s < 5; ++s) {
        if (s * 64 + lane < 264)
            __builtin_amdgcn_global_load_lds(
                (const __attribute__((address_space(1))) void*)(xt_g + src_off[s]),
                (__attribute__((address_space(3))) void*)&xt[0][(wv * 264 + s * 64) * 8],
                16, 0, 0);
    }

    for (int ch = 0; ch < 8; ++ch) {
        if (ch < 7) {  // stage next chunk into other buffer
            const ushort* sp = xt_g + (ch + 1) * 32;
#pragma unroll
            for (int s = 0; s < 5; ++s) {
                if (s * 64 + lane < 264)
                    __builtin_amdgcn_global_load_lds(
                        (const __attribute__((address_space(1))) void*)(sp + src_off[s]),
                        (__attribute__((address_space(3))) void*)&xt[(ch + 1) & 1][(wv * 264 + s * 64) * 8],
                        16, 0, 0);
            }
            asm volatile("s_waitcnt vmcnt(5)" ::: "memory");  // chunk ch landed
        } else {
            asm volatile("s_waitcnt vmcnt(0)" ::: "memory");
        }
        __builtin_amdgcn_s_barrier();

        const ushort* buf = xt[ch & 1];
#pragma unroll
        for (int kh = 0; kh < 3; ++kh) {
#pragma unroll
            for (int kw = 0; kw < 3; ++kw) {
                const int t = kh * 3 + kw;
#pragma unroll
                for (int k2 = 0; k2 < 2; ++k2) {
                    const int kb = k2 * 2 + hi;
                    const short* ap = W2 + (size_t)(((ch * 9 + t) * 4 + kb) * 256 + co0 + wm + l31) * 8;
                    short8 a0 = *(const short8*)ap;
                    short8 a1 = *(const short8*)(ap + 32 * 8);

                    const int c  = kw + l31;
                    const int r  = wn + kh;
                    const ushort* bp = &buf[((r * 66 + c) * 4 + (kb ^ ((c >> 1) & 3))) * 8];
                    short8 b0 = *(const short8*)bp;
                    short8 b1 = *(const short8*)(bp + 32 * 4 * 8);  // +32 cols: swizzle invariant

                    acc[0][0] = __builtin_amdgcn_mfma_f32_32x32x16_bf16(a0, b0, acc[0][0], 0, 0, 0);
                    acc[0][1] = __builtin_amdgcn_mfma_f32_32x32x16_bf16(a0, b1, acc[0][1], 0, 0, 0);
                    acc[1][0] = __builtin_amdgcn_mfma_f32_32x32x16_bf16(a1, b0, acc[1][0], 0, 0, 0);
                    acc[1][1] = __builtin_amdgcn_mfma_f32_32x32x16_bf16(a1, b1, acc[1][1], 0, 0, 0);
                }
            }
        }
        asm volatile("s_waitcnt lgkmcnt(0)" ::: "memory");  // my LDS reads done
        __builtin_amdgcn_s_barrier();                       // all waves done reading
    }

    // epilogue: D col=lane&31 -> n(w), row=(j&3)+8*(j>>2)+4*hi -> co
    const int h = h0 + wn;
#pragma unroll
    for (int a = 0; a < 2; ++a) {
#pragma unroll
        for (int f = 0; f < 2; ++f) {
            int w = f * 32 + l31;
            if (w < HW) {
#pragma unroll
                for (int j = 0; j < 16; ++j) {
                    int co = co0 + wm + a * 32 + (j & 3) + 8 * (j >> 2) + 4 * hi;
                    out[(((size_t)b * CO + co) * HW + h) * HW + w] = acc[a][f][j];
                }
            }
        }
    }
}

// ---------------- Fallback (round-2 verbatim): in-kernel cvt, 16x16 MFMA ----------------
__global__ __launch_bounds__(256, 2) void conv_mfma_fb(const float* __restrict__ x,
                                                       const short* __restrict__ W2,
                                                       float* __restrict__ out) {
    __shared__ __align__(16) short xs[6 * 72 * 32];

    const int tid  = threadIdx.x;
    const int lane = tid & 63;
    const int wv   = tid >> 6;
    const int l15  = lane & 15;
    const int kb   = lane >> 4;
    const int wm    = (wv >> 1) * 64;
    const int wnrow = (wv & 1) * 2;

    const int h0  = blockIdx.x * 4;
    const int co0 = blockIdx.y * 128;
    const int b   = blockIdx.z;

    f32x4 acc[4][8];
#pragma unroll
    for (int a = 0; a < 4; ++a)
#pragma unroll
        for (int f = 0; f < 8; ++f) acc[a][f] = (f32x4){0.f, 0.f, 0.f, 0.f};

    const float* xb = x + (size_t)b * CI * HW * HW;

    for (int ch = 0; ch < 8; ++ch) {
        const int ci0 = ch * 32;
        for (int f = tid; f < 6 * 66; f += 256) {
            int r = f / 66, c = f % 66;
            int h = h0 - 1 + r, wc = c - 1;
            bool valid = (h >= 0) & (h < HW) & (wc >= 0) & (wc < HW);
            const float* xsrc = xb + (size_t)ci0 * 3136 + (valid ? (h * HW + wc) : 0);
            int sw = (c >> 1) & 3;
            int sbase = (r * 72 + c) * 32;
#pragma unroll
            for (int k = 0; k < 4; ++k) {
                short8 pk;
#pragma unroll
                for (int e = 0; e < 8; ++e) {
                    float v = xsrc[(size_t)(k * 8 + e) * 3136];
                    pk[e] = (short)f2bf(valid ? v : 0.f);
                }
                *(short8*)&xs[sbase + ((k ^ sw) * 8)] = pk;
            }
        }
        __syncthreads();

#pragma unroll
        for (int kh = 0; kh < 3; ++kh) {
#pragma unroll
            for (int kw = 0; kw < 3; ++kw) {
                const int t = kh * 3 + kw;
                const short* ap = W2 + (size_t)((((ch * 9 + t) * 4 + kb) * 256) + co0 + wm + l15) * 8;
                short8 af[4];
#pragma unroll
                for (int a = 0; a < 4; ++a) af[a] = *(const short8*)(ap + a * 128);

                const int c0 = kw + l15;
                const int r0 = wnrow + kh;
                const short* bp = &xs[(r0 * 72 + c0) * 32 + ((kb ^ ((c0 >> 1) & 3)) * 8)];
                short8 bf[8];
#pragma unroll
                for (int f = 0; f < 8; ++f)
                    bf[f] = *(const short8*)(bp + (f >> 2) * 2304 + (f & 3) * 512);

#pragma unroll
                for (int a = 0; a < 4; ++a)
#pragma unroll
                    for (int f = 0; f < 8; ++f)
                        acc[a][f] = __builtin_amdgcn_mfma_f32_16x16x32_bf16(af[a], bf[f], acc[a][f], 0, 0, 0);
            }
        }
        __syncthreads();
    }

#pragma unroll
    for (int a = 0; a < 4; ++a) {
#pragma unroll
        for (int f = 0; f < 8; ++f) {
            int wloc = (f & 3) * 16 + l15;
            if (wloc < HW) {
                int h = h0 + wnrow + (f >> 2);
#pragma unroll
                for (int j = 0; j < 4; ++j) {
                    int cog = co0 + wm + 16 * a + kb * 4 + j;
                    out[(((size_t)b * CO + cog) * HW + h) * HW + wloc] = acc[a][f][j];
                }
            }
        }
    }
}

extern "C" void kernel_launch(void* const* d_in, const int* in_sizes, int n_in,
                              void* d_out, int out_size, void* d_ws, size_t ws_size,
                              hipStream_t stream) {
    const float* x       = (const float*)d_in[0]; // (32,256,56,56)
    const float* p_c     = (const float*)d_in[1]; // (256,256,3,3,7)
    const float* q_level = (const float*)d_in[2]; // (7,)
    float* out = (float*)d_out;

    short* W2 = (short*)d_ws;                          // 1.18 MB at offset 0
    const size_t XT_OFF = 2u * 1024 * 1024;
    const size_t need = XT_OFF + (size_t)32 * 3364 * 256 * 2;  // + 55.1 MB NHWC bf16

    quant_weights<<<(CO * CI * 9 + 255) / 256, 256, 0, stream>>>(p_c, q_level, W2);

    if (ws_size >= need) {
        ushort* xt_g = (ushort*)((char*)d_ws + XT_OFF);
        prep_main<<<dim3(56, 32), 256, 0, stream>>>(x, xt_g);
        conv_mfma3<<<dim3(28, 2, 32), 256, 0, stream>>>(xt_g, W2, out);
    } else {
        conv_mfma_fb<<<dim3(14, 2, 32), 256, 0, stream>>>(x, W2, out);
    }
}